// Round 15
// baseline (304.245 us; speedup 1.0000x reference)
//
#include <hip/hip_runtime.h>
#include <hip/hip_bf16.h>
#include <math.h>

#define H 128
#define NTPB 256
#define NBKT 256      // dst buckets, 512 nodes each
#define BSH 9
#define BMSK 511
#define EPB 8192      // edges per partition block
#define EPBKT 10240   // padded slots per bucket (mean 8192, +22 sigma)
#define SRC_MASK 0x1FFFFu
#define NPW 8         // nodes per wave in l2_gather

typedef __attribute__((ext_vector_type(8))) short short8;
typedef __attribute__((ext_vector_type(4))) float floatx4;
typedef __attribute__((ext_vector_type(2))) float f2v;

__device__ __forceinline__ void atomAddF(float* p, float v) {
    __hip_atomic_fetch_add(p, v, __ATOMIC_RELAXED, __HIP_MEMORY_SCOPE_AGENT);
}

__device__ __forceinline__ short f2bf(float v) {
    __hip_bfloat16 b = __float2bfloat16(v);
    return __builtin_bit_cast(short, b);
}

__device__ __forceinline__ f2v splat2(float v) { return (f2v){v, v}; }

// ---- CSR build pass 1: partition edges into PADDED bucket regions.
// Self-counting via gcursor atomics (no hist/scan pre-passes needed):
// bucket b's edges land at ebuf[b*EPBKT ... b*EPBKT+count). LDS ranks keep
// the writes in ~128B runs per bucket. Last 8 blocks do the W2 bpack.
__global__ void partition_kernel(const int* __restrict__ ei, int E,
                                 int* __restrict__ gcursor, unsigned* __restrict__ ebuf,
                                 const float* __restrict__ W2,
                                 __hip_bfloat16* __restrict__ Bp, int EB) {
    int t = threadIdx.x;
    if (blockIdx.x >= EB) {
        int idx = (blockIdx.x - EB) * NTPB + t;  // 0..2047
        if (idx < 2048) {
            int frag = idx >> 6, lane = idx & 63;
            int nt = frag >> 2, c = frag & 3, quad = lane >> 4, m16 = lane & 15;
#pragma unroll
            for (int jj = 0; jj < 8; jj++) {
                int k = c * 32 + quad * 8 + jj;
                Bp[idx * 8 + jj] = __float2bfloat16(W2[k * H + nt * 16 + m16]);
            }
        }
        return;
    }
    __shared__ int lcur[NBKT];
    __shared__ int lbase[NBKT];
    lcur[t] = 0;
    __syncthreads();
    int base = blockIdx.x * EPB;
    unsigned short rk[EPB / NTPB];
#pragma unroll
    for (int k = 0; k < EPB / NTPB; k++) {
        int e = base + k * NTPB + t;
        rk[k] = 0;
        if (e < E) rk[k] = (unsigned short)atomicAdd(&lcur[((unsigned)ei[E + e]) >> BSH], 1);
    }
    __syncthreads();
    lbase[t] = atomicAdd(&gcursor[t], lcur[t]);
    __syncthreads();
#pragma unroll
    for (int k = 0; k < EPB / NTPB; k++) {
        int e = base + k * NTPB + t;
        if (e < E) {
            unsigned d = (unsigned)ei[E + e];
            unsigned s = (unsigned)ei[e];
            int bkt = d >> BSH;
            ebuf[(size_t)bkt * EPBKT + lbase[bkt] + rk[k]] = ((d & BMSK) << 17) | s;
        }
    }
}

// ---- CSR build pass 2: per-bucket LDS counting sort -> rowptr, csr, xs4.
// Computes its own global prefix from the bucket counts (256-wide LDS scan,
// ~1us, parallel across blocks) -> hist/scan_buckets kernels eliminated.
__global__ void bucket_sort(const unsigned* __restrict__ ebuf, const int* __restrict__ gcursor,
                            const float* __restrict__ x,
                            int* __restrict__ rowptr, unsigned* __restrict__ csr,
                            float4* __restrict__ xs4, int N) {
    __shared__ int ldeg[512];
    __shared__ int loff[512];
    __shared__ int sd[NTPB];
    __shared__ int sbeg;
    int t = threadIdx.x, b = blockIdx.x;
    // global prefix of bucket counts
    int v = gcursor[t];
    sd[t] = v; __syncthreads();
    for (int s = 1; s < NBKT; s <<= 1) {
        int u = (t >= s) ? sd[t - s] : 0;
        __syncthreads();
        sd[t] += u;
        __syncthreads();
    }
    if (t == b) sbeg = sd[t] - v;  // exclusive prefix for this bucket (b < 256)
    ldeg[t] = 0; ldeg[t + 256] = 0;
    __syncthreads();
    int beg = sbeg;
    int cnt = gcursor[b];
    int node0 = b << BSH;
    const unsigned* eb = ebuf + (size_t)b * EPBKT;
    for (int i = t; i < cnt; i += NTPB)
        atomicAdd(&ldeg[eb[i] >> 17], 1);
    __syncthreads();
    int d0 = ldeg[2 * t], d1 = ldeg[2 * t + 1];
    int ps = d0 + d1;
    sd[t] = ps; __syncthreads();
    for (int s = 1; s < NTPB; s <<= 1) {
        int u = (t >= s) ? sd[t - s] : 0;
        __syncthreads();
        sd[t] += u;
        __syncthreads();
    }
    int ex = sd[t] - ps;
    loff[2 * t] = ex;
    loff[2 * t + 1] = ex + d0;
    __syncthreads();
    for (int i = t; i < 512; i += NTPB) {
        int node = node0 + i;
        if (node < N) {
            rowptr[node] = beg + loff[i];
            float dv = rsqrtf((float)(ldeg[i] + 1));
            xs4[node] = make_float4(x[3 * node] * dv, x[3 * node + 1] * dv,
                                    x[3 * node + 2] * dv, dv);
        } else if (node == N) {
            rowptr[N] = beg + loff[i];  // == E
        }
    }
    __syncthreads();
    for (int i = t; i < cnt; i += NTPB) {
        unsigned u = eb[i];
        int pos = beg + atomicAdd(&loff[u >> 17], 1);
        csr[pos] = u & 0x1FFFFu;
    }
}

// layer-1 gather: aggx[d] = dinv[d] * (sum_e xs[s] + xs[d]); unweighted adds
__global__ void l1_gather(const float4* __restrict__ xs4,
                          const int* __restrict__ rowptr, const unsigned* __restrict__ csr,
                          float4* __restrict__ aggx4, int N) {
    int n = blockIdx.x * blockDim.x + threadIdx.x;
    if (n >= N) return;
    float4 xn = xs4[n];
    float a0 = xn.x, a1 = xn.y, a2 = xn.z;
    int beg = rowptr[n], end = rowptr[n + 1];
    int i = beg;
    for (; i + 4 <= end; i += 4) {
        float4 q0 = xs4[csr[i]];
        float4 q1 = xs4[csr[i + 1]];
        float4 q2 = xs4[csr[i + 2]];
        float4 q3 = xs4[csr[i + 3]];
        a0 += q0.x + q1.x + q2.x + q3.x;
        a1 += q0.y + q1.y + q2.y + q3.y;
        a2 += q0.z + q1.z + q2.z + q3.z;
    }
    for (; i < end; ++i) {
        float4 q = xs4[csr[i]];
        a0 += q.x; a1 += q.y; a2 += q.z;
    }
    float dv = xn.w;
    aggx4[n] = make_float4(a0 * dv, a1 * dv, a2 * dv, dv);
}

// per-edge layer-2 work: z = relu(p@W1+b1) on this lane's 2 dims; acc += p.w*z.
__device__ __forceinline__ void edge_accs(float px, float py, float pz, float pw,
                                          const f2v wa, const f2v wb, const f2v wc,
                                          const f2v bb, f2v& acc) {
    f2v z = __builtin_elementwise_fma(splat2(px), wa, bb);
    z = __builtin_elementwise_fma(splat2(py), wb, z);
    z = __builtin_elementwise_fma(splat2(pz), wc, z);
    z = __builtin_elementwise_max(z, (f2v){0.f, 0.f});
    acc = __builtin_elementwise_fma(splat2(pw), z, acc);
}

// FUSED layer-2 gather — R12 measured-best form (44us), unchanged.
__global__ void l2_gather(
        const float4* __restrict__ aggx4,
        const int* __restrict__ rowptr, const unsigned* __restrict__ csr,
        const float* __restrict__ W1, const float* __restrict__ b1,
        __hip_bfloat16* __restrict__ agg1, int N) {
    __shared__ float4 sbuf[NTPB / 64][2][64];  // 8KB: two 64-edge windows per wave
    __shared__ float4 sown[NTPB / 64][NPW];    // self rows
    int t = threadIdx.x;
    int lane = t & 63;
    int w = t >> 6;
    int n0 = (blockIdx.x * (NTPB / 64) + w) * NPW;
    if (n0 >= N) return;
    int k0 = 2 * lane;
    f2v wa = *(const f2v*)&W1[k0];
    f2v wb = *(const f2v*)&W1[H + k0];
    f2v wc = *(const f2v*)&W1[2 * H + k0];
    f2v bb = *(const f2v*)&b1[k0];
    int rp[NPW + 1];
#pragma unroll
    for (int nd = 0; nd <= NPW; nd++) rp[nd] = rowptr[min(n0 + nd, N)];
    if (lane < NPW) sown[w][lane] = aggx4[min(n0 + lane, N - 1)];
    f2v accs[NPW];
#pragma unroll
    for (int nd = 0; nd < NPW; nd++) accs[nd] = (f2v){0.f, 0.f};
    int beg = rp[0], end = rp[NPW];
    if (beg < end) {
        sbuf[w][0][lane] = aggx4[csr[beg + lane] & SRC_MASK];
    }
    unsigned cB = csr[beg + 64 + lane];  // csr +256 slack keeps this in-bounds
    int cur = 0;
    for (int win = beg; win < end; win += 64) {
        int nwin = win + 64;
        float4 rn;
        bool have_next = nwin < end;
        if (have_next) rn = aggx4[cB & SRC_MASK];
        unsigned cNN = csr[win + 128 + lane];
        int wend = min(nwin, end);
#pragma unroll
        for (int nd = 0; nd < NPW; nd++) {
            int s = max(rp[nd], win);
            int e2 = min(rp[nd + 1], wend);
            int e = s;
            for (; e + 4 <= e2; e += 4) {
                float4 p0 = sbuf[w][cur][e - win];
                float4 p1 = sbuf[w][cur][e - win + 1];
                float4 p2 = sbuf[w][cur][e - win + 2];
                float4 p3 = sbuf[w][cur][e - win + 3];
                edge_accs(p0.x, p0.y, p0.z, p0.w, wa, wb, wc, bb, accs[nd]);
                edge_accs(p1.x, p1.y, p1.z, p1.w, wa, wb, wc, bb, accs[nd]);
                edge_accs(p2.x, p2.y, p2.z, p2.w, wa, wb, wc, bb, accs[nd]);
                edge_accs(p3.x, p3.y, p3.z, p3.w, wa, wb, wc, bb, accs[nd]);
            }
            for (; e < e2; ++e) {
                float4 p = sbuf[w][cur][e - win];
                edge_accs(p.x, p.y, p.z, p.w, wa, wb, wc, bb, accs[nd]);
            }
        }
        if (have_next) sbuf[w][cur ^ 1][lane] = rn;
        cB = cNN;
        cur ^= 1;
    }
#pragma unroll
    for (int nd = 0; nd < NPW; nd++) {
        int n = n0 + nd;
        if (n < N) {
            float4 own = sown[w][nd];
            edge_accs(own.x, own.y, own.z, own.w, wa, wb, wc, bb, accs[nd]);
            f2v r = accs[nd] * splat2(own.w);
            unsigned packed = ((unsigned)(unsigned short)f2bf(r.x)) |
                              ((unsigned)(unsigned short)f2bf(r.y) << 16);
            ((unsigned*)agg1)[(size_t)n * (H / 2) + lane] = packed;
        }
    }
}

// Final MFMA + FUSED pool + output: h2 = relu(agg1@W2+b2); dot with Wc; the
// block's <=64 node-dots are LDS-privatized per graph (sorted batch => ~2-3
// graphs/block => ~2-3 global atomic pairs), last block (ticket) writes the
// sigmoid output. No nodedot round-trip, no separate pool/out launches.
// NOTE: no early return -- all 256 threads stay alive through the barriers;
// out-of-range rows are guarded per access (af zeroed, stores masked).
__global__ __launch_bounds__(NTPB, 4) void gemm_pool(
        const __hip_bfloat16* __restrict__ agg1, const __hip_bfloat16* __restrict__ Bp,
        const float* __restrict__ b2, const float* __restrict__ Wc,
        const int* __restrict__ batch,
        float* __restrict__ gsum, int* __restrict__ gcnt,
        int* __restrict__ done, const float* __restrict__ bc,
        float* __restrict__ out, int N, int G, int nblocks) {
    __shared__ float sb2[H];
    __shared__ float swc[H];
    __shared__ int amLast;
    extern __shared__ char sm[];
    float* ls = (float*)sm;
    int*   lc = (int*)(sm + (size_t)G * sizeof(float));
    int t = threadIdx.x;
    if (t < H) { sb2[t] = b2[t]; swc[t] = Wc[t]; }
    for (int g = t; g < G; g += NTPB) { ls[g] = 0.f; lc[g] = 0; }
    __syncthreads();
    int wave = t >> 6, lane = t & 63;
    int quad = lane >> 4, m16 = lane & 15;
    int tile = blockIdx.x * 4 + wave;
    int rowbase = tile * 16;
    int m = rowbase + m16;
    const short8* as8 = (const short8*)agg1;
    short8 af[4];
    if (m < N) {
#pragma unroll
        for (int c = 0; c < 4; c++) af[c] = as8[(size_t)m * 16 + c * 4 + quad];
    } else {
#pragma unroll
        for (int c = 0; c < 4; c++) af[c] = (short8){0, 0, 0, 0, 0, 0, 0, 0};
    }
    const short8* bp = (const short8*)Bp;
    floatx4 acc[8];
#pragma unroll
    for (int nt = 0; nt < 8; nt++) acc[nt] = (floatx4){0.f, 0.f, 0.f, 0.f};
#pragma unroll
    for (int nt = 0; nt < 8; nt++) {
#pragma unroll
        for (int c = 0; c < 4; c++) {
            short8 bf = bp[(nt * 4 + c) * 64 + lane];
            acc[nt] = __builtin_amdgcn_mfma_f32_16x16x32_bf16(af[c], bf, acc[nt], 0, 0, 0);
        }
    }
    float dot0 = 0.f, dot1 = 0.f, dot2 = 0.f, dot3 = 0.f;
#pragma unroll
    for (int nt = 0; nt < 8; nt++) {
        int col = nt * 16 + m16;
        float bcol = sb2[col], wcol = swc[col];
        dot0 += fmaxf(acc[nt][0] + bcol, 0.f) * wcol;
        dot1 += fmaxf(acc[nt][1] + bcol, 0.f) * wcol;
        dot2 += fmaxf(acc[nt][2] + bcol, 0.f) * wcol;
        dot3 += fmaxf(acc[nt][3] + bcol, 0.f) * wcol;
    }
#pragma unroll
    for (int s = 1; s < 16; s <<= 1) {
        dot0 += __shfl_xor(dot0, s);
        dot1 += __shfl_xor(dot1, s);
        dot2 += __shfl_xor(dot2, s);
        dot3 += __shfl_xor(dot3, s);
    }
    if (m16 < 4) {
        int row = rowbase + quad * 4 + m16;
        if (row < N) {
            float d = (m16 == 0) ? dot0 : (m16 == 1) ? dot1 : (m16 == 2) ? dot2 : dot3;
            int g = batch[row];
            atomicAdd(&ls[g], d);
            atomicAdd(&lc[g], 1);
        }
    }
    __syncthreads();
    for (int g = t; g < G; g += NTPB) {
        if (lc[g] != 0) {
            atomAddF(&gsum[g], ls[g]);
            atomicAdd(&gcnt[g], lc[g]);
        }
    }
    __threadfence();  // publish my atomics before taking a ticket
    if (t == 0) {
        int ticket = __hip_atomic_fetch_add(done, 1, __ATOMIC_ACQ_REL,
                                            __HIP_MEMORY_SCOPE_AGENT);
        amLast = (ticket == nblocks - 1);
    }
    __syncthreads();
    if (amLast) {
        __threadfence();  // acquire: all other blocks' atomics now visible
        for (int g = t; g < G; g += NTPB) {
            float s = __hip_atomic_load(&gsum[g], __ATOMIC_RELAXED,
                                        __HIP_MEMORY_SCOPE_AGENT);
            int cc = __hip_atomic_load(&gcnt[g], __ATOMIC_RELAXED,
                                       __HIP_MEMORY_SCOPE_AGENT);
            float c = fmaxf((float)cc, 1.f);
            float logit = s / c + bc[0];
            out[g] = 1.f / (1.f + expf(-logit));
        }
    }
}

extern "C" void kernel_launch(void* const* d_in, const int* in_sizes, int n_in,
                              void* d_out, int out_size, void* d_ws, size_t ws_size,
                              hipStream_t stream) {
    const float* x     = (const float*)d_in[0];
    const int*   ei    = (const int*)d_in[1];
    const int*   batch = (const int*)d_in[2];
    const float* W1    = (const float*)d_in[3];
    const float* b1    = (const float*)d_in[4];
    const float* W2    = (const float*)d_in[5];
    const float* b2    = (const float*)d_in[6];
    const float* Wc    = (const float*)d_in[7];
    const float* bc    = (const float*)d_in[8];
    float* out = (float*)d_out;

    int N = in_sizes[2];
    int E = in_sizes[1] / 2;
    int G = out_size;

    char* ws = (char*)d_ws;
    size_t off = 0;
    auto alloc = [&](size_t bytes) {
        void* p = ws + off;
        off += (bytes + 255) & ~(size_t)255;
        return p;
    };
    __hip_bfloat16* agg1 = (__hip_bfloat16*)alloc((size_t)N * H * sizeof(__hip_bfloat16));
    float4* xs4   = (float4*)alloc((size_t)N * sizeof(float4));
    float4* aggx4 = (float4*)alloc((size_t)(SRC_MASK + 1) * sizeof(float4));
    // zeroed block: gsum/gcnt/gcursor/done contiguous -> single memset
    float* gsum   = (float*)alloc((size_t)G * sizeof(float));
    int*   gcnt   = (int*)  alloc((size_t)G * sizeof(int));
    int*   gcursor= (int*)  alloc((size_t)NBKT * sizeof(int));
    int*   done   = (int*)  alloc(sizeof(int));
    char*  zero_end = ws + off;
    int*   rowptr = (int*)  alloc((size_t)(N + 1) * sizeof(int));
    unsigned* csr = (unsigned*)alloc((size_t)(E + 256) * sizeof(unsigned));
    unsigned* ebuf= (unsigned*)alloc((size_t)NBKT * EPBKT * sizeof(unsigned));
    __hip_bfloat16* Bp = (__hip_bfloat16*)alloc((size_t)H * H * sizeof(__hip_bfloat16));

    (void)hipMemsetAsync(gsum, 0, (size_t)(zero_end - (char*)gsum), stream);

    int EB = (E + EPB - 1) / EPB;
    partition_kernel<<<EB + 8, NTPB, 0, stream>>>(ei, E, gcursor, ebuf, W2, Bp, EB);
    {
        int nbs = (N >> BSH) + 1;
        bucket_sort<<<nbs, NTPB, 0, stream>>>(ebuf, gcursor, x, rowptr, csr, xs4, N);
    }

    l1_gather<<<(N + NTPB - 1) / NTPB, NTPB, 0, stream>>>(xs4, rowptr, csr, aggx4, N);

    {
        int npb = NPW * (NTPB / 64);  // 32 nodes per block
        int blocks = (N + npb - 1) / npb;
        l2_gather<<<blocks, NTPB, 0, stream>>>(aggx4, rowptr, csr, W1, b1, agg1, N);
    }

    {
        int ntiles = (N + 15) / 16;
        int nblocks = (ntiles + 3) / 4;
        size_t smem = (size_t)G * (sizeof(float) + sizeof(int));
        gemm_pool<<<nblocks, NTPB, smem, stream>>>(agg1, Bp, b2, Wc, batch,
                                                   gsum, gcnt, done, bc, out,
                                                   N, G, nblocks);
    }
}

// Round 16
// 204.993 us; speedup vs baseline: 1.4842x; 1.4842x over previous
//
#include <hip/hip_runtime.h>
#include <hip/hip_bf16.h>
#include <math.h>

#define H 128
#define NTPB 256
#define NBKT 256      // dst buckets, 512 nodes each
#define BSH 9
#define BMSK 511
#define EPB 8192      // edges per partition block
#define EPBKT 10240   // padded slots per bucket (mean 8192, +22 sigma)
#define POOL_CHUNK 2048
#define SRC_MASK 0x1FFFFu
#define NPW 8         // nodes per wave in l2_gather

typedef __attribute__((ext_vector_type(8))) short short8;
typedef __attribute__((ext_vector_type(4))) float floatx4;
typedef __attribute__((ext_vector_type(2))) float f2v;

__device__ __forceinline__ void atomAddF(float* p, float v) {
    __hip_atomic_fetch_add(p, v, __ATOMIC_RELAXED, __HIP_MEMORY_SCOPE_AGENT);
}

__device__ __forceinline__ short f2bf(float v) {
    __hip_bfloat16 b = __float2bfloat16(v);
    return __builtin_bit_cast(short, b);
}

__device__ __forceinline__ f2v splat2(float v) { return (f2v){v, v}; }

// ---- CSR build pass 1: partition edges into PADDED bucket regions.
// Self-counting via gcursor atomics (no hist/scan pre-passes): bucket b's
// edges land at ebuf[b*EPBKT ...). Last 8 blocks do the W2 bpack.
// (R15 measured: this 2-pass build saved ~19us vs the 4-pass chain.)
__global__ void partition_kernel(const int* __restrict__ ei, int E,
                                 int* __restrict__ gcursor, unsigned* __restrict__ ebuf,
                                 const float* __restrict__ W2,
                                 __hip_bfloat16* __restrict__ Bp, int EB) {
    int t = threadIdx.x;
    if (blockIdx.x >= EB) {
        int idx = (blockIdx.x - EB) * NTPB + t;  // 0..2047
        if (idx < 2048) {
            int frag = idx >> 6, lane = idx & 63;
            int nt = frag >> 2, c = frag & 3, quad = lane >> 4, m16 = lane & 15;
#pragma unroll
            for (int jj = 0; jj < 8; jj++) {
                int k = c * 32 + quad * 8 + jj;
                Bp[idx * 8 + jj] = __float2bfloat16(W2[k * H + nt * 16 + m16]);
            }
        }
        return;
    }
    __shared__ int lcur[NBKT];
    __shared__ int lbase[NBKT];
    lcur[t] = 0;
    __syncthreads();
    int base = blockIdx.x * EPB;
    unsigned short rk[EPB / NTPB];
#pragma unroll
    for (int k = 0; k < EPB / NTPB; k++) {
        int e = base + k * NTPB + t;
        rk[k] = 0;
        if (e < E) rk[k] = (unsigned short)atomicAdd(&lcur[((unsigned)ei[E + e]) >> BSH], 1);
    }
    __syncthreads();
    lbase[t] = atomicAdd(&gcursor[t], lcur[t]);
    __syncthreads();
#pragma unroll
    for (int k = 0; k < EPB / NTPB; k++) {
        int e = base + k * NTPB + t;
        if (e < E) {
            unsigned d = (unsigned)ei[E + e];
            unsigned s = (unsigned)ei[e];
            int bkt = d >> BSH;
            ebuf[(size_t)bkt * EPBKT + lbase[bkt] + rk[k]] = ((d & BMSK) << 17) | s;
        }
    }
}

// ---- CSR build pass 2: per-bucket LDS counting sort -> rowptr, csr, xs4.
// Computes its own global prefix from bucket counts (in-block 256-wide scan).
__global__ void bucket_sort(const unsigned* __restrict__ ebuf, const int* __restrict__ gcursor,
                            const float* __restrict__ x,
                            int* __restrict__ rowptr, unsigned* __restrict__ csr,
                            float4* __restrict__ xs4, int N) {
    __shared__ int ldeg[512];
    __shared__ int loff[512];
    __shared__ int sd[NTPB];
    __shared__ int sbeg;
    int t = threadIdx.x, b = blockIdx.x;
    int v = gcursor[t];
    sd[t] = v; __syncthreads();
    for (int s = 1; s < NBKT; s <<= 1) {
        int u = (t >= s) ? sd[t - s] : 0;
        __syncthreads();
        sd[t] += u;
        __syncthreads();
    }
    if (t == b) sbeg = sd[t] - v;  // exclusive prefix for this bucket (b < 256)
    ldeg[t] = 0; ldeg[t + 256] = 0;
    __syncthreads();
    int beg = sbeg;
    int cnt = gcursor[b];
    int node0 = b << BSH;
    const unsigned* eb = ebuf + (size_t)b * EPBKT;
    for (int i = t; i < cnt; i += NTPB)
        atomicAdd(&ldeg[eb[i] >> 17], 1);
    __syncthreads();
    int d0 = ldeg[2 * t], d1 = ldeg[2 * t + 1];
    int ps = d0 + d1;
    sd[t] = ps; __syncthreads();
    for (int s = 1; s < NTPB; s <<= 1) {
        int u = (t >= s) ? sd[t - s] : 0;
        __syncthreads();
        sd[t] += u;
        __syncthreads();
    }
    int ex = sd[t] - ps;
    loff[2 * t] = ex;
    loff[2 * t + 1] = ex + d0;
    __syncthreads();
    for (int i = t; i < 512; i += NTPB) {
        int node = node0 + i;
        if (node < N) {
            rowptr[node] = beg + loff[i];
            float dv = rsqrtf((float)(ldeg[i] + 1));
            xs4[node] = make_float4(x[3 * node] * dv, x[3 * node + 1] * dv,
                                    x[3 * node + 2] * dv, dv);
        } else if (node == N) {
            rowptr[N] = beg + loff[i];  // == E
        }
    }
    __syncthreads();
    for (int i = t; i < cnt; i += NTPB) {
        unsigned u = eb[i];
        int pos = beg + atomicAdd(&loff[u >> 17], 1);
        csr[pos] = u & 0x1FFFFu;
    }
}

// layer-1 gather: aggx[d] = dinv[d] * (sum_e xs[s] + xs[d]); unweighted adds
__global__ void l1_gather(const float4* __restrict__ xs4,
                          const int* __restrict__ rowptr, const unsigned* __restrict__ csr,
                          float4* __restrict__ aggx4, int N) {
    int n = blockIdx.x * blockDim.x + threadIdx.x;
    if (n >= N) return;
    float4 xn = xs4[n];
    float a0 = xn.x, a1 = xn.y, a2 = xn.z;
    int beg = rowptr[n], end = rowptr[n + 1];
    int i = beg;
    for (; i + 4 <= end; i += 4) {
        float4 q0 = xs4[csr[i]];
        float4 q1 = xs4[csr[i + 1]];
        float4 q2 = xs4[csr[i + 2]];
        float4 q3 = xs4[csr[i + 3]];
        a0 += q0.x + q1.x + q2.x + q3.x;
        a1 += q0.y + q1.y + q2.y + q3.y;
        a2 += q0.z + q1.z + q2.z + q3.z;
    }
    for (; i < end; ++i) {
        float4 q = xs4[csr[i]];
        a0 += q.x; a1 += q.y; a2 += q.z;
    }
    float dv = xn.w;
    aggx4[n] = make_float4(a0 * dv, a1 * dv, a2 * dv, dv);
}

// per-edge layer-2 work: z = relu(p@W1+b1) on this lane's 2 dims; acc += p.w*z.
__device__ __forceinline__ void edge_accs(float px, float py, float pz, float pw,
                                          const f2v wa, const f2v wb, const f2v wc,
                                          const f2v bb, f2v& acc) {
    f2v z = __builtin_elementwise_fma(splat2(px), wa, bb);
    z = __builtin_elementwise_fma(splat2(py), wb, z);
    z = __builtin_elementwise_fma(splat2(pz), wc, z);
    z = __builtin_elementwise_max(z, (f2v){0.f, 0.f});
    acc = __builtin_elementwise_fma(splat2(pw), z, acc);
}

// FUSED layer-2 gather — R12 measured-best form (44us), unchanged.
__global__ void l2_gather(
        const float4* __restrict__ aggx4,
        const int* __restrict__ rowptr, const unsigned* __restrict__ csr,
        const float* __restrict__ W1, const float* __restrict__ b1,
        __hip_bfloat16* __restrict__ agg1, int N) {
    __shared__ float4 sbuf[NTPB / 64][2][64];  // 8KB: two 64-edge windows per wave
    __shared__ float4 sown[NTPB / 64][NPW];    // self rows
    int t = threadIdx.x;
    int lane = t & 63;
    int w = t >> 6;
    int n0 = (blockIdx.x * (NTPB / 64) + w) * NPW;
    if (n0 >= N) return;
    int k0 = 2 * lane;
    f2v wa = *(const f2v*)&W1[k0];
    f2v wb = *(const f2v*)&W1[H + k0];
    f2v wc = *(const f2v*)&W1[2 * H + k0];
    f2v bb = *(const f2v*)&b1[k0];
    int rp[NPW + 1];
#pragma unroll
    for (int nd = 0; nd <= NPW; nd++) rp[nd] = rowptr[min(n0 + nd, N)];
    if (lane < NPW) sown[w][lane] = aggx4[min(n0 + lane, N - 1)];
    f2v accs[NPW];
#pragma unroll
    for (int nd = 0; nd < NPW; nd++) accs[nd] = (f2v){0.f, 0.f};
    int beg = rp[0], end = rp[NPW];
    if (beg < end) {
        sbuf[w][0][lane] = aggx4[csr[beg + lane] & SRC_MASK];
    }
    unsigned cB = csr[beg + 64 + lane];  // csr +256 slack keeps this in-bounds
    int cur = 0;
    for (int win = beg; win < end; win += 64) {
        int nwin = win + 64;
        float4 rn;
        bool have_next = nwin < end;
        if (have_next) rn = aggx4[cB & SRC_MASK];
        unsigned cNN = csr[win + 128 + lane];
        int wend = min(nwin, end);
#pragma unroll
        for (int nd = 0; nd < NPW; nd++) {
            int s = max(rp[nd], win);
            int e2 = min(rp[nd + 1], wend);
            int e = s;
            for (; e + 4 <= e2; e += 4) {
                float4 p0 = sbuf[w][cur][e - win];
                float4 p1 = sbuf[w][cur][e - win + 1];
                float4 p2 = sbuf[w][cur][e - win + 2];
                float4 p3 = sbuf[w][cur][e - win + 3];
                edge_accs(p0.x, p0.y, p0.z, p0.w, wa, wb, wc, bb, accs[nd]);
                edge_accs(p1.x, p1.y, p1.z, p1.w, wa, wb, wc, bb, accs[nd]);
                edge_accs(p2.x, p2.y, p2.z, p2.w, wa, wb, wc, bb, accs[nd]);
                edge_accs(p3.x, p3.y, p3.z, p3.w, wa, wb, wc, bb, accs[nd]);
            }
            for (; e < e2; ++e) {
                float4 p = sbuf[w][cur][e - win];
                edge_accs(p.x, p.y, p.z, p.w, wa, wb, wc, bb, accs[nd]);
            }
        }
        if (have_next) sbuf[w][cur ^ 1][lane] = rn;
        cB = cNN;
        cur ^= 1;
    }
#pragma unroll
    for (int nd = 0; nd < NPW; nd++) {
        int n = n0 + nd;
        if (n < N) {
            float4 own = sown[w][nd];
            edge_accs(own.x, own.y, own.z, own.w, wa, wb, wc, bb, accs[nd]);
            f2v r = accs[nd] * splat2(own.w);
            unsigned packed = ((unsigned)(unsigned short)f2bf(r.x)) |
                              ((unsigned)(unsigned short)f2bf(r.y) << 16);
            ((unsigned*)agg1)[(size_t)n * (H / 2) + lane] = packed;
        }
    }
}

// Final MFMA: h2 = relu(agg1 @ W2 + b2); dot with Wc -> nodedot[row].
// NO atomics/fences here: R15's fused version put a device-scope threadfence
// (L2 writeback) in all 1563 blocks -> 129us fence-bound. Keep it clean.
__global__ __launch_bounds__(NTPB, 4) void gemm_nodedot(
        const __hip_bfloat16* __restrict__ agg1, const __hip_bfloat16* __restrict__ Bp,
        const float* __restrict__ b2, const float* __restrict__ Wc,
        float* __restrict__ nodedot, int N) {
    __shared__ float sb2[H];
    __shared__ float swc[H];
    int t = threadIdx.x;
    if (t < H) { sb2[t] = b2[t]; swc[t] = Wc[t]; }
    __syncthreads();
    int wave = t >> 6, lane = t & 63;
    int quad = lane >> 4, m16 = lane & 15;
    int tile = blockIdx.x * 4 + wave;
    int rowbase = tile * 16;
    if (rowbase >= N) return;
    int m = rowbase + m16;
    const short8* as8 = (const short8*)agg1;
    short8 af[4];
    if (m < N) {
#pragma unroll
        for (int c = 0; c < 4; c++) af[c] = as8[(size_t)m * 16 + c * 4 + quad];
    } else {
#pragma unroll
        for (int c = 0; c < 4; c++) af[c] = (short8){0, 0, 0, 0, 0, 0, 0, 0};
    }
    const short8* bp = (const short8*)Bp;
    floatx4 acc[8];
#pragma unroll
    for (int nt = 0; nt < 8; nt++) acc[nt] = (floatx4){0.f, 0.f, 0.f, 0.f};
#pragma unroll
    for (int nt = 0; nt < 8; nt++) {
#pragma unroll
        for (int c = 0; c < 4; c++) {
            short8 bf = bp[(nt * 4 + c) * 64 + lane];
            acc[nt] = __builtin_amdgcn_mfma_f32_16x16x32_bf16(af[c], bf, acc[nt], 0, 0, 0);
        }
    }
    float dot0 = 0.f, dot1 = 0.f, dot2 = 0.f, dot3 = 0.f;
#pragma unroll
    for (int nt = 0; nt < 8; nt++) {
        int col = nt * 16 + m16;
        float bcol = sb2[col], wcol = swc[col];
        dot0 += fmaxf(acc[nt][0] + bcol, 0.f) * wcol;
        dot1 += fmaxf(acc[nt][1] + bcol, 0.f) * wcol;
        dot2 += fmaxf(acc[nt][2] + bcol, 0.f) * wcol;
        dot3 += fmaxf(acc[nt][3] + bcol, 0.f) * wcol;
    }
#pragma unroll
    for (int s = 1; s < 16; s <<= 1) {
        dot0 += __shfl_xor(dot0, s);
        dot1 += __shfl_xor(dot1, s);
        dot2 += __shfl_xor(dot2, s);
        dot3 += __shfl_xor(dot3, s);
    }
    if (m16 < 4) {
        int row = rowbase + quad * 4 + m16;
        if (row < N) {
            float d = (m16 == 0) ? dot0 : (m16 == 1) ? dot1 : (m16 == 2) ? dot2 : dot3;
            nodedot[row] = d;
        }
    }
}

// segmented mean-pool + fused sigmoid output (R14 measured form): 49 blocks,
// LDS-privatized accumulation, ~12 global atomic pairs/block, last block
// (device-scope ticket) writes the output. Fence count = 49, cheap.
__global__ void pool_kernel(const float* __restrict__ nodedot, const int* __restrict__ batch,
                            float* __restrict__ gsum, int* __restrict__ gcnt,
                            int* __restrict__ done, const float* __restrict__ bc,
                            float* __restrict__ out, int N, int G, int pblocks) {
    extern __shared__ char sm[];
    float* ls = (float*)sm;
    int*   lc = (int*)(sm + (size_t)G * sizeof(float));
    __shared__ int amLast;
    int t = threadIdx.x;
    for (int g = t; g < G; g += blockDim.x) { ls[g] = 0.f; lc[g] = 0; }
    __syncthreads();
    int base = blockIdx.x * POOL_CHUNK;
    int endn = min(base + POOL_CHUNK, N);
    for (int n = base + t; n < endn; n += blockDim.x) {
        int g = batch[n];
        atomicAdd(&ls[g], nodedot[n]);
        atomicAdd(&lc[g], 1);
    }
    __syncthreads();
    for (int g = t; g < G; g += blockDim.x) {
        if (lc[g] != 0) {
            atomAddF(&gsum[g], ls[g]);
            atomicAdd(&gcnt[g], lc[g]);
        }
    }
    __threadfence();  // publish my atomics before taking a ticket
    if (t == 0) {
        int ticket = __hip_atomic_fetch_add(done, 1, __ATOMIC_ACQ_REL,
                                            __HIP_MEMORY_SCOPE_AGENT);
        amLast = (ticket == pblocks - 1);
    }
    __syncthreads();
    if (amLast) {
        __threadfence();  // acquire: all other blocks' atomics now visible
        for (int g = t; g < G; g += blockDim.x) {
            float s = __hip_atomic_load(&gsum[g], __ATOMIC_RELAXED,
                                        __HIP_MEMORY_SCOPE_AGENT);
            int cc = __hip_atomic_load(&gcnt[g], __ATOMIC_RELAXED,
                                       __HIP_MEMORY_SCOPE_AGENT);
            float c = fmaxf((float)cc, 1.f);
            float logit = s / c + bc[0];
            out[g] = 1.f / (1.f + expf(-logit));
        }
    }
}

extern "C" void kernel_launch(void* const* d_in, const int* in_sizes, int n_in,
                              void* d_out, int out_size, void* d_ws, size_t ws_size,
                              hipStream_t stream) {
    const float* x     = (const float*)d_in[0];
    const int*   ei    = (const int*)d_in[1];
    const int*   batch = (const int*)d_in[2];
    const float* W1    = (const float*)d_in[3];
    const float* b1    = (const float*)d_in[4];
    const float* W2    = (const float*)d_in[5];
    const float* b2    = (const float*)d_in[6];
    const float* Wc    = (const float*)d_in[7];
    const float* bc    = (const float*)d_in[8];
    float* out = (float*)d_out;

    int N = in_sizes[2];
    int E = in_sizes[1] / 2;
    int G = out_size;

    char* ws = (char*)d_ws;
    size_t off = 0;
    auto alloc = [&](size_t bytes) {
        void* p = ws + off;
        off += (bytes + 255) & ~(size_t)255;
        return p;
    };
    __hip_bfloat16* agg1 = (__hip_bfloat16*)alloc((size_t)N * H * sizeof(__hip_bfloat16));
    float4* xs4   = (float4*)alloc((size_t)N * sizeof(float4));
    float4* aggx4 = (float4*)alloc((size_t)(SRC_MASK + 1) * sizeof(float4));
    float* nodedot= (float*)alloc((size_t)N * sizeof(float));
    // zeroed block: gsum/gcnt/gcursor/done contiguous -> single memset
    float* gsum   = (float*)alloc((size_t)G * sizeof(float));
    int*   gcnt   = (int*)  alloc((size_t)G * sizeof(int));
    int*   gcursor= (int*)  alloc((size_t)NBKT * sizeof(int));
    int*   done   = (int*)  alloc(sizeof(int));
    char*  zero_end = ws + off;
    int*   rowptr = (int*)  alloc((size_t)(N + 1) * sizeof(int));
    unsigned* csr = (unsigned*)alloc((size_t)(E + 256) * sizeof(unsigned));
    unsigned* ebuf= (unsigned*)alloc((size_t)NBKT * EPBKT * sizeof(unsigned));
    __hip_bfloat16* Bp = (__hip_bfloat16*)alloc((size_t)H * H * sizeof(__hip_bfloat16));

    (void)hipMemsetAsync(gsum, 0, (size_t)(zero_end - (char*)gsum), stream);

    int EB = (E + EPB - 1) / EPB;
    partition_kernel<<<EB + 8, NTPB, 0, stream>>>(ei, E, gcursor, ebuf, W2, Bp, EB);
    {
        int nbs = (N >> BSH) + 1;
        bucket_sort<<<nbs, NTPB, 0, stream>>>(ebuf, gcursor, x, rowptr, csr, xs4, N);
    }

    l1_gather<<<(N + NTPB - 1) / NTPB, NTPB, 0, stream>>>(xs4, rowptr, csr, aggx4, N);

    {
        int npb = NPW * (NTPB / 64);  // 32 nodes per block
        int blocks = (N + npb - 1) / npb;
        l2_gather<<<blocks, NTPB, 0, stream>>>(aggx4, rowptr, csr, W1, b1, agg1, N);
    }

    {
        int ntiles = (N + 15) / 16;
        gemm_nodedot<<<(ntiles + 3) / 4, NTPB, 0, stream>>>(agg1, Bp, b2, Wc, nodedot, N);
    }

    {
        int pblocks = (N + POOL_CHUNK - 1) / POOL_CHUNK;
        size_t smem = (size_t)G * (sizeof(float) + sizeof(int));
        pool_kernel<<<pblocks, NTPB, smem, stream>>>(nodedot, batch, gsum, gcnt,
                                                     done, bc, out, N, G, pblocks);
    }
}

// Round 17
// 195.747 us; speedup vs baseline: 1.5543x; 1.0472x over previous
//
#include <hip/hip_runtime.h>
#include <hip/hip_bf16.h>
#include <math.h>

#define H 128
#define NTPB 256
#define NBKT 256      // dst buckets, 512 nodes each
#define BSH 9
#define BMSK 511
#define EPB 8192      // edges per partition block
#define EPBKT 10240   // padded slots per bucket (mean 8192, +22 sigma)
#define SRC_MASK 0x1FFFFu
#define NPW 8         // nodes per wave in l2_gather

typedef __attribute__((ext_vector_type(8))) short short8;
typedef __attribute__((ext_vector_type(4))) float floatx4;
typedef __attribute__((ext_vector_type(2))) float f2v;

__device__ __forceinline__ void atomAddF(float* p, float v) {
    __hip_atomic_fetch_add(p, v, __ATOMIC_RELAXED, __HIP_MEMORY_SCOPE_AGENT);
}

__device__ __forceinline__ short f2bf(float v) {
    __hip_bfloat16 b = __float2bfloat16(v);
    return __builtin_bit_cast(short, b);
}

__device__ __forceinline__ f2v splat2(float v) { return (f2v){v, v}; }

// ---- CSR build pass 1: partition edges into PADDED bucket regions.
// Self-counting via gcursor atomics (no hist/scan pre-passes): bucket b's
// edges land at ebuf[b*EPBKT ...). Last 8 blocks do the W2 bpack.
__global__ void partition_kernel(const int* __restrict__ ei, int E,
                                 int* __restrict__ gcursor, unsigned* __restrict__ ebuf,
                                 const float* __restrict__ W2,
                                 __hip_bfloat16* __restrict__ Bp, int EB) {
    int t = threadIdx.x;
    if (blockIdx.x >= EB) {
        int idx = (blockIdx.x - EB) * NTPB + t;  // 0..2047
        if (idx < 2048) {
            int frag = idx >> 6, lane = idx & 63;
            int nt = frag >> 2, c = frag & 3, quad = lane >> 4, m16 = lane & 15;
#pragma unroll
            for (int jj = 0; jj < 8; jj++) {
                int k = c * 32 + quad * 8 + jj;
                Bp[idx * 8 + jj] = __float2bfloat16(W2[k * H + nt * 16 + m16]);
            }
        }
        return;
    }
    __shared__ int lcur[NBKT];
    __shared__ int lbase[NBKT];
    lcur[t] = 0;
    __syncthreads();
    int base = blockIdx.x * EPB;
    unsigned short rk[EPB / NTPB];
#pragma unroll
    for (int k = 0; k < EPB / NTPB; k++) {
        int e = base + k * NTPB + t;
        rk[k] = 0;
        if (e < E) rk[k] = (unsigned short)atomicAdd(&lcur[((unsigned)ei[E + e]) >> BSH], 1);
    }
    __syncthreads();
    lbase[t] = atomicAdd(&gcursor[t], lcur[t]);
    __syncthreads();
#pragma unroll
    for (int k = 0; k < EPB / NTPB; k++) {
        int e = base + k * NTPB + t;
        if (e < E) {
            unsigned d = (unsigned)ei[E + e];
            unsigned s = (unsigned)ei[e];
            int bkt = d >> BSH;
            ebuf[(size_t)bkt * EPBKT + lbase[bkt] + rk[k]] = ((d & BMSK) << 17) | s;
        }
    }
}

// ---- CSR build pass 2: per-bucket LDS counting sort -> rowptr, csr, xs4.
// Computes its own global prefix from bucket counts (in-block 256-wide scan).
__global__ void bucket_sort(const unsigned* __restrict__ ebuf, const int* __restrict__ gcursor,
                            const float* __restrict__ x,
                            int* __restrict__ rowptr, unsigned* __restrict__ csr,
                            float4* __restrict__ xs4, int N) {
    __shared__ int ldeg[512];
    __shared__ int loff[512];
    __shared__ int sd[NTPB];
    __shared__ int sbeg;
    int t = threadIdx.x, b = blockIdx.x;
    int v = gcursor[t];
    sd[t] = v; __syncthreads();
    for (int s = 1; s < NBKT; s <<= 1) {
        int u = (t >= s) ? sd[t - s] : 0;
        __syncthreads();
        sd[t] += u;
        __syncthreads();
    }
    if (t == b) sbeg = sd[t] - v;  // exclusive prefix for this bucket (b < 256)
    ldeg[t] = 0; ldeg[t + 256] = 0;
    __syncthreads();
    int beg = sbeg;
    int cnt = gcursor[b];
    int node0 = b << BSH;
    const unsigned* eb = ebuf + (size_t)b * EPBKT;
    for (int i = t; i < cnt; i += NTPB)
        atomicAdd(&ldeg[eb[i] >> 17], 1);
    __syncthreads();
    int d0 = ldeg[2 * t], d1 = ldeg[2 * t + 1];
    int ps = d0 + d1;
    sd[t] = ps; __syncthreads();
    for (int s = 1; s < NTPB; s <<= 1) {
        int u = (t >= s) ? sd[t - s] : 0;
        __syncthreads();
        sd[t] += u;
        __syncthreads();
    }
    int ex = sd[t] - ps;
    loff[2 * t] = ex;
    loff[2 * t + 1] = ex + d0;
    __syncthreads();
    for (int i = t; i < 512; i += NTPB) {
        int node = node0 + i;
        if (node < N) {
            rowptr[node] = beg + loff[i];
            float dv = rsqrtf((float)(ldeg[i] + 1));
            xs4[node] = make_float4(x[3 * node] * dv, x[3 * node + 1] * dv,
                                    x[3 * node + 2] * dv, dv);
        } else if (node == N) {
            rowptr[N] = beg + loff[i];  // == E
        }
    }
    __syncthreads();
    for (int i = t; i < cnt; i += NTPB) {
        unsigned u = eb[i];
        int pos = beg + atomicAdd(&loff[u >> 17], 1);
        csr[pos] = u & 0x1FFFFu;
    }
}

// layer-1 gather: aggx[d] = dinv[d] * (sum_e xs[s] + xs[d]); unweighted adds
__global__ void l1_gather(const float4* __restrict__ xs4,
                          const int* __restrict__ rowptr, const unsigned* __restrict__ csr,
                          float4* __restrict__ aggx4, int N) {
    int n = blockIdx.x * blockDim.x + threadIdx.x;
    if (n >= N) return;
    float4 xn = xs4[n];
    float a0 = xn.x, a1 = xn.y, a2 = xn.z;
    int beg = rowptr[n], end = rowptr[n + 1];
    int i = beg;
    for (; i + 4 <= end; i += 4) {
        float4 q0 = xs4[csr[i]];
        float4 q1 = xs4[csr[i + 1]];
        float4 q2 = xs4[csr[i + 2]];
        float4 q3 = xs4[csr[i + 3]];
        a0 += q0.x + q1.x + q2.x + q3.x;
        a1 += q0.y + q1.y + q2.y + q3.y;
        a2 += q0.z + q1.z + q2.z + q3.z;
    }
    for (; i < end; ++i) {
        float4 q = xs4[csr[i]];
        a0 += q.x; a1 += q.y; a2 += q.z;
    }
    float dv = xn.w;
    aggx4[n] = make_float4(a0 * dv, a1 * dv, a2 * dv, dv);
}

// per-edge layer-2 work: z = relu(p@W1+b1) on this lane's 2 dims; acc += p.w*z.
__device__ __forceinline__ void edge_accs(float px, float py, float pz, float pw,
                                          const f2v wa, const f2v wb, const f2v wc,
                                          const f2v bb, f2v& acc) {
    f2v z = __builtin_elementwise_fma(splat2(px), wa, bb);
    z = __builtin_elementwise_fma(splat2(py), wb, z);
    z = __builtin_elementwise_fma(splat2(pz), wc, z);
    z = __builtin_elementwise_max(z, (f2v){0.f, 0.f});
    acc = __builtin_elementwise_fma(splat2(pw), z, acc);
}

// FUSED layer-2 gather — R12 measured-best form (44us), unchanged.
__global__ void l2_gather(
        const float4* __restrict__ aggx4,
        const int* __restrict__ rowptr, const unsigned* __restrict__ csr,
        const float* __restrict__ W1, const float* __restrict__ b1,
        __hip_bfloat16* __restrict__ agg1, int N) {
    __shared__ float4 sbuf[NTPB / 64][2][64];  // 8KB: two 64-edge windows per wave
    __shared__ float4 sown[NTPB / 64][NPW];    // self rows
    int t = threadIdx.x;
    int lane = t & 63;
    int w = t >> 6;
    int n0 = (blockIdx.x * (NTPB / 64) + w) * NPW;
    if (n0 >= N) return;
    int k0 = 2 * lane;
    f2v wa = *(const f2v*)&W1[k0];
    f2v wb = *(const f2v*)&W1[H + k0];
    f2v wc = *(const f2v*)&W1[2 * H + k0];
    f2v bb = *(const f2v*)&b1[k0];
    int rp[NPW + 1];
#pragma unroll
    for (int nd = 0; nd <= NPW; nd++) rp[nd] = rowptr[min(n0 + nd, N)];
    if (lane < NPW) sown[w][lane] = aggx4[min(n0 + lane, N - 1)];
    f2v accs[NPW];
#pragma unroll
    for (int nd = 0; nd < NPW; nd++) accs[nd] = (f2v){0.f, 0.f};
    int beg = rp[0], end = rp[NPW];
    if (beg < end) {
        sbuf[w][0][lane] = aggx4[csr[beg + lane] & SRC_MASK];
    }
    unsigned cB = csr[beg + 64 + lane];  // csr +256 slack keeps this in-bounds
    int cur = 0;
    for (int win = beg; win < end; win += 64) {
        int nwin = win + 64;
        float4 rn;
        bool have_next = nwin < end;
        if (have_next) rn = aggx4[cB & SRC_MASK];
        unsigned cNN = csr[win + 128 + lane];
        int wend = min(nwin, end);
#pragma unroll
        for (int nd = 0; nd < NPW; nd++) {
            int s = max(rp[nd], win);
            int e2 = min(rp[nd + 1], wend);
            int e = s;
            for (; e + 4 <= e2; e += 4) {
                float4 p0 = sbuf[w][cur][e - win];
                float4 p1 = sbuf[w][cur][e - win + 1];
                float4 p2 = sbuf[w][cur][e - win + 2];
                float4 p3 = sbuf[w][cur][e - win + 3];
                edge_accs(p0.x, p0.y, p0.z, p0.w, wa, wb, wc, bb, accs[nd]);
                edge_accs(p1.x, p1.y, p1.z, p1.w, wa, wb, wc, bb, accs[nd]);
                edge_accs(p2.x, p2.y, p2.z, p2.w, wa, wb, wc, bb, accs[nd]);
                edge_accs(p3.x, p3.y, p3.z, p3.w, wa, wb, wc, bb, accs[nd]);
            }
            for (; e < e2; ++e) {
                float4 p = sbuf[w][cur][e - win];
                edge_accs(p.x, p.y, p.z, p.w, wa, wb, wc, bb, accs[nd]);
            }
        }
        if (have_next) sbuf[w][cur ^ 1][lane] = rn;
        cB = cNN;
        cur ^= 1;
    }
#pragma unroll
    for (int nd = 0; nd < NPW; nd++) {
        int n = n0 + nd;
        if (n < N) {
            float4 own = sown[w][nd];
            edge_accs(own.x, own.y, own.z, own.w, wa, wb, wc, bb, accs[nd]);
            f2v r = accs[nd] * splat2(own.w);
            unsigned packed = ((unsigned)(unsigned short)f2bf(r.x)) |
                              ((unsigned)(unsigned short)f2bf(r.y) << 16);
            ((unsigned*)agg1)[(size_t)n * (H / 2) + lane] = packed;
        }
    }
}

// Final MFMA + LDS-privatized pool tail: h2 = relu(agg1@W2+b2); dot with Wc;
// block's <=64 node-dots accumulate in LDS per graph (sorted batch => ~2-3
// graphs/block => ~2-3 agent-scope atomic pairs/block, ~3.6k total on 512
// addrs). NO fence, NO ticket — R15's 129us was the per-block L2-writeback
// threadfence, not the atomics; kernel-boundary ordering covers visibility
// for out_kernel. No early return (divergent-barrier hazard): per-access
// guards only, all 256 threads reach every __syncthreads.
__global__ __launch_bounds__(NTPB, 4) void gemm_pool(
        const __hip_bfloat16* __restrict__ agg1, const __hip_bfloat16* __restrict__ Bp,
        const float* __restrict__ b2, const float* __restrict__ Wc,
        const int* __restrict__ batch,
        float* __restrict__ gsum, int* __restrict__ gcnt, int N, int G) {
    __shared__ float sb2[H];
    __shared__ float swc[H];
    extern __shared__ char sm[];
    float* ls = (float*)sm;
    int*   lc = (int*)(sm + (size_t)G * sizeof(float));
    int t = threadIdx.x;
    if (t < H) { sb2[t] = b2[t]; swc[t] = Wc[t]; }
    for (int g = t; g < G; g += NTPB) { ls[g] = 0.f; lc[g] = 0; }
    __syncthreads();
    int wave = t >> 6, lane = t & 63;
    int quad = lane >> 4, m16 = lane & 15;
    int tile = blockIdx.x * 4 + wave;
    int rowbase = tile * 16;
    int m = rowbase + m16;
    const short8* as8 = (const short8*)agg1;
    short8 af[4];
    if (m < N) {
#pragma unroll
        for (int c = 0; c < 4; c++) af[c] = as8[(size_t)m * 16 + c * 4 + quad];
    } else {
#pragma unroll
        for (int c = 0; c < 4; c++) af[c] = (short8){0, 0, 0, 0, 0, 0, 0, 0};
    }
    const short8* bp = (const short8*)Bp;
    floatx4 acc[8];
#pragma unroll
    for (int nt = 0; nt < 8; nt++) acc[nt] = (floatx4){0.f, 0.f, 0.f, 0.f};
#pragma unroll
    for (int nt = 0; nt < 8; nt++) {
#pragma unroll
        for (int c = 0; c < 4; c++) {
            short8 bf = bp[(nt * 4 + c) * 64 + lane];
            acc[nt] = __builtin_amdgcn_mfma_f32_16x16x32_bf16(af[c], bf, acc[nt], 0, 0, 0);
        }
    }
    float dot0 = 0.f, dot1 = 0.f, dot2 = 0.f, dot3 = 0.f;
#pragma unroll
    for (int nt = 0; nt < 8; nt++) {
        int col = nt * 16 + m16;
        float bcol = sb2[col], wcol = swc[col];
        dot0 += fmaxf(acc[nt][0] + bcol, 0.f) * wcol;
        dot1 += fmaxf(acc[nt][1] + bcol, 0.f) * wcol;
        dot2 += fmaxf(acc[nt][2] + bcol, 0.f) * wcol;
        dot3 += fmaxf(acc[nt][3] + bcol, 0.f) * wcol;
    }
#pragma unroll
    for (int s = 1; s < 16; s <<= 1) {
        dot0 += __shfl_xor(dot0, s);
        dot1 += __shfl_xor(dot1, s);
        dot2 += __shfl_xor(dot2, s);
        dot3 += __shfl_xor(dot3, s);
    }
    if (m16 < 4) {
        int row = rowbase + quad * 4 + m16;
        if (row < N) {
            float d = (m16 == 0) ? dot0 : (m16 == 1) ? dot1 : (m16 == 2) ? dot2 : dot3;
            int g = batch[row];
            atomicAdd(&ls[g], d);
            atomicAdd(&lc[g], 1);
        }
    }
    __syncthreads();
    for (int g = t; g < G; g += NTPB) {
        if (lc[g] != 0) {
            atomAddF(&gsum[g], ls[g]);
            atomicAdd(&gcnt[g], lc[g]);
        }
    }
}

__global__ void out_kernel(const float* __restrict__ gsum, const int* __restrict__ gcnt,
                           const float* __restrict__ bc, float* __restrict__ out, int G) {
    int g = blockIdx.x * blockDim.x + threadIdx.x;
    if (g >= G) return;
    float c = fmaxf((float)gcnt[g], 1.f);
    float logit = gsum[g] / c + bc[0];
    out[g] = 1.f / (1.f + expf(-logit));
}

extern "C" void kernel_launch(void* const* d_in, const int* in_sizes, int n_in,
                              void* d_out, int out_size, void* d_ws, size_t ws_size,
                              hipStream_t stream) {
    const float* x     = (const float*)d_in[0];
    const int*   ei    = (const int*)d_in[1];
    const int*   batch = (const int*)d_in[2];
    const float* W1    = (const float*)d_in[3];
    const float* b1    = (const float*)d_in[4];
    const float* W2    = (const float*)d_in[5];
    const float* b2    = (const float*)d_in[6];
    const float* Wc    = (const float*)d_in[7];
    const float* bc    = (const float*)d_in[8];
    float* out = (float*)d_out;

    int N = in_sizes[2];
    int E = in_sizes[1] / 2;
    int G = out_size;

    char* ws = (char*)d_ws;
    size_t off = 0;
    auto alloc = [&](size_t bytes) {
        void* p = ws + off;
        off += (bytes + 255) & ~(size_t)255;
        return p;
    };
    __hip_bfloat16* agg1 = (__hip_bfloat16*)alloc((size_t)N * H * sizeof(__hip_bfloat16));
    float4* xs4   = (float4*)alloc((size_t)N * sizeof(float4));
    float4* aggx4 = (float4*)alloc((size_t)(SRC_MASK + 1) * sizeof(float4));
    // zeroed block: gsum/gcnt/gcursor contiguous -> single memset
    float* gsum   = (float*)alloc((size_t)G * sizeof(float));
    int*   gcnt   = (int*)  alloc((size_t)G * sizeof(int));
    int*   gcursor= (int*)  alloc((size_t)NBKT * sizeof(int));
    char*  zero_end = ws + off;
    int*   rowptr = (int*)  alloc((size_t)(N + 1) * sizeof(int));
    unsigned* csr = (unsigned*)alloc((size_t)(E + 256) * sizeof(unsigned));
    unsigned* ebuf= (unsigned*)alloc((size_t)NBKT * EPBKT * sizeof(unsigned));
    __hip_bfloat16* Bp = (__hip_bfloat16*)alloc((size_t)H * H * sizeof(__hip_bfloat16));

    (void)hipMemsetAsync(gsum, 0, (size_t)(zero_end - (char*)gsum), stream);

    int EB = (E + EPB - 1) / EPB;
    partition_kernel<<<EB + 8, NTPB, 0, stream>>>(ei, E, gcursor, ebuf, W2, Bp, EB);
    {
        int nbs = (N >> BSH) + 1;
        bucket_sort<<<nbs, NTPB, 0, stream>>>(ebuf, gcursor, x, rowptr, csr, xs4, N);
    }

    l1_gather<<<(N + NTPB - 1) / NTPB, NTPB, 0, stream>>>(xs4, rowptr, csr, aggx4, N);

    {
        int npb = NPW * (NTPB / 64);  // 32 nodes per block
        int blocks = (N + npb - 1) / npb;
        l2_gather<<<blocks, NTPB, 0, stream>>>(aggx4, rowptr, csr, W1, b1, agg1, N);
    }

    {
        int ntiles = (N + 15) / 16;
        int nblocks = (ntiles + 3) / 4;
        size_t smem = (size_t)G * (sizeof(float) + sizeof(int));
        gemm_pool<<<nblocks, NTPB, smem, stream>>>(agg1, Bp, b2, Wc, batch,
                                                   gsum, gcnt, N, G);
    }

    out_kernel<<<(G + NTPB - 1) / NTPB, NTPB, 0, stream>>>(gsum, gcnt, bc, out, G);
}